// Round 3
// baseline (212.090 us; speedup 1.0000x reference)
//
#include <hip/hip_runtime.h>

// Reprojection residual, round 3.
//
// R1 (global scalar pose gather): 78 us. R2 (LDS pose gather): 82 us.
// => pose gather path is NOT the bottleneck; all pipes idle => bound on
// cache-line request service + dependent-load latency of the streaming side.
//
// This round:
//  - prep kernel pads poses 7->8 floats in d_ws => pose gather is 2 aligned
//    float4 loads instead of 7 scalars (3.5x fewer line requests; 64 KB
//    padded table is L2-resident).
//  - 8 points/thread, 256-thr blocks, one-shot grid, no LDS/barrier, all
//    independent loads hoisted so ~40 loads are in flight per thread.

#define BLOCK 256

__global__ void pad_poses_kernel(const float* __restrict__ poses,
                                 float4* __restrict__ ptab, int C) {
    int j = blockIdx.x * blockDim.x + threadIdx.x;
    if (j >= C) return;
    const float* p = poses + 7L * j;
    ptab[2 * j]     = make_float4(p[0], p[1], p[2], p[3]); // t.xyz, qx
    ptab[2 * j + 1] = make_float4(p[4], p[5], p[6], 0.0f); // qy, qz, qw, pad
}

__global__ __launch_bounds__(BLOCK) void residual_kernel(
    const float4* __restrict__ ptab,   // padded poses, 2 float4 per pose
    const float*  __restrict__ pts,
    const float4* __restrict__ obs4,
    const float*  __restrict__ Km,
    const int4*   __restrict__ cidx4,
    const int4*   __restrict__ pidx4,
    float4*       __restrict__ out4,
    int n8)   // number of 8-point groups
{
    int t = blockIdx.x * BLOCK + threadIdx.x;
    if (t >= n8) return;

    // ---- wave 1 of loads: indices + observations (independent) ----
    int4 ci_lo = cidx4[2 * t];
    int4 ci_hi = cidx4[2 * t + 1];
    int4 pi_lo = pidx4[2 * t];
    int4 pi_hi = pidx4[2 * t + 1];
    float4 ob[4];
    #pragma unroll
    for (int j = 0; j < 4; ++j) ob[j] = obs4[4 * t + j];

    float k00 = Km[0], k01 = Km[1], k02 = Km[2];
    float k10 = Km[3], k11 = Km[4], k12 = Km[5];
    float k20 = Km[6], k21 = Km[7], k22 = Km[8];

    int cis[8] = {ci_lo.x, ci_lo.y, ci_lo.z, ci_lo.w,
                  ci_hi.x, ci_hi.y, ci_hi.z, ci_hi.w};
    int pis[8] = {pi_lo.x, pi_lo.y, pi_lo.z, pi_lo.w,
                  pi_hi.x, pi_hi.y, pi_hi.z, pi_hi.w};

    // ---- wave 2 of loads: 16 pose float4 + 24 point dwords, all in flight ----
    float4 plo[8], phi[8];
    #pragma unroll
    for (int j = 0; j < 8; ++j) {
        plo[j] = ptab[2 * cis[j]];
        phi[j] = ptab[2 * cis[j] + 1];
    }
    float px[8], py[8], pz[8];
    #pragma unroll
    for (int j = 0; j < 8; ++j) {
        const float* pp = pts + 3L * (long)pis[j];
        px[j] = pp[0]; py[j] = pp[1]; pz[j] = pp[2];
    }

    // ---- compute ----
    float res[16];
    #pragma unroll
    for (int j = 0; j < 8; ++j) {
        float tx = plo[j].x, ty = plo[j].y, tz = plo[j].z;
        float qx = plo[j].w, qy = phi[j].x, qz = phi[j].y, qw = phi[j].z;
        float X = px[j], Y = py[j], Z = pz[j];

        // uv = cross(qv, p) + qw * p
        float ux = qy * Z - qz * Y + qw * X;
        float uy = qz * X - qx * Z + qw * Y;
        float uz = qx * Y - qy * X + qw * Z;

        // pc = p + 2*cross(qv, uv) + t
        float cx = X + 2.0f * (qy * uz - qz * uy) + tx;
        float cy = Y + 2.0f * (qz * ux - qx * uz) + ty;
        float cz = Z + 2.0f * (qx * uy - qy * ux) + tz;

        // proj = K @ pc ; pix = proj.xy / proj.z
        float w    = k20 * cx + k21 * cy + k22 * cz;
        float invw = __builtin_amdgcn_rcpf(w);
        float u    = (k00 * cx + k01 * cy + k02 * cz) * invw;
        float v    = (k10 * cx + k11 * cy + k12 * cz) * invw;

        float2 o  = make_float2(u, v);
        res[2 * j]     = o.x;
        res[2 * j + 1] = o.y;
    }

    // subtract observations
    res[0]  -= ob[0].x; res[1]  -= ob[0].y; res[2]  -= ob[0].z; res[3]  -= ob[0].w;
    res[4]  -= ob[1].x; res[5]  -= ob[1].y; res[6]  -= ob[1].z; res[7]  -= ob[1].w;
    res[8]  -= ob[2].x; res[9]  -= ob[2].y; res[10] -= ob[2].z; res[11] -= ob[2].w;
    res[12] -= ob[3].x; res[13] -= ob[3].y; res[14] -= ob[3].z; res[15] -= ob[3].w;

    // ---- store 4 x float4 ----
    #pragma unroll
    for (int j = 0; j < 4; ++j)
        out4[4 * t + j] = make_float4(res[4 * j], res[4 * j + 1],
                                      res[4 * j + 2], res[4 * j + 3]);
}

extern "C" void kernel_launch(void* const* d_in, const int* in_sizes, int n_in,
                              void* d_out, int out_size, void* d_ws, size_t ws_size,
                              hipStream_t stream) {
    const float* poses = (const float*)d_in[0];
    const float* pts   = (const float*)d_in[1];
    const float* obs   = (const float*)d_in[2];
    const float* Km    = (const float*)d_in[3];
    const int*   cidx  = (const int*)d_in[4];
    const int*   pidx  = (const int*)d_in[5];
    float* out = (float*)d_out;

    int P  = in_sizes[4];       // 5,000,000 points
    int C  = in_sizes[0] / 7;   // 2000 poses
    int n8 = P / 8;             // 625,000 (exact)

    float4* ptab = (float4*)d_ws;   // C * 32 B = 64 KB

    pad_poses_kernel<<<(C + BLOCK - 1) / BLOCK, BLOCK, 0, stream>>>(poses, ptab, C);

    int grid = (n8 + BLOCK - 1) / BLOCK;
    residual_kernel<<<grid, BLOCK, 0, stream>>>(
        ptab, pts, (const float4*)obs, Km,
        (const int4*)cidx, (const int4*)pidx, (float4*)out, n8);
}